// Round 6
// baseline (510.173 us; speedup 1.0000x reference)
//
#include <hip/hip_runtime.h>

typedef unsigned short u16;
typedef __attribute__((ext_vector_type(8)))  short          short8;
typedef __attribute__((ext_vector_type(8)))  unsigned short ushort8v;
typedef __attribute__((ext_vector_type(4)))  unsigned short ushort4v;
typedef __attribute__((ext_vector_type(16))) float          float16v;

__device__ __forceinline__ float bf2f(u16 u){
  union { unsigned int i; float f; } x; x.i = ((unsigned int)u) << 16; return x.f;
}
__device__ __forceinline__ u16 f2bf(float f){
  union { float f; unsigned int i; } x; x.f = f;
  unsigned int u = x.i;
  unsigned int r = (u + 0x7FFFu + ((u >> 16) & 1u)) >> 16;
  return (u16)r;
}
__device__ __forceinline__ float lk(float v){ return v > 0.f ? v : 0.01f*v; }

// ---------------- weight permute+quantize: Wmat[o][j*C+c] = bf16(W[o][c][j]) --
// ws layout (bf16 elems): Wmat1 @0 (256x384), Wmat2 @98304 (128x768), Wmat3 @196608 (64x384)
__global__ void permute_w(const float* __restrict__ W1, const float* __restrict__ W2,
                          const float* __restrict__ W3, u16* __restrict__ ws){
  int t = blockIdx.x*256 + threadIdx.x;
  const float* src; u16* dst; int C, local;
  if (t < 98304)       { src = W1; dst = ws;          C = 128; local = t; }
  else if (t < 196608) { src = W2; dst = ws + 98304;  C = 256; local = t - 98304; }
  else if (t < 221184) { src = W3; dst = ws + 196608; C = 128; local = t - 196608; }
  else return;
  int K3 = 3*C;
  int o = local / K3, r = local - o*K3;
  int j = r / C,      c = r - j*C;
  dst[local] = f2bf(src[o*K3 + c*3 + j]);
}

// ---------------- fused per-tree layer (4 waves, in-register output) ----------
// GEMM out[O x 127] = Wmat[O x 3C] * G, where G[j*C+c][m] = bIn[idx[3m+j]][c]
// Wave w -> row-block (w*NTL)>>2 (32*PAIR rows), n-tiles (w*NTL)&3 .. +NTL.
// PAIR = MFMAs fed per B-fragment (LDS-read amortization). Output stays in acc
// until after the stats __syncthreads (fences k-loop LDS reads), THEN is
// written to bOut/bOutF — which may ALIAS bIn.
template<int CIN, int O, int SIN, int OST, int PAIR, int NTL, bool LEAKY, bool IS_L3>
__device__ __forceinline__ void do_layer(const u16* __restrict__ Wm,
                                         const float* __restrict__ bias,
                                         const u16* bIn, u16* bOut, float* bOutF,
                                         const int* sidx, float* sstat,
                                         int tid, float* out_mean, float* out_inv)
{
  constexpr int K3  = 3*CIN;
  constexpr int KS  = CIN/16;     // k-steps per j segment
  constexpr int NJK = K3/16;      // total k-steps
  // total work units (row-blocks x 4 n-tiles) must equal 4 waves x NTL
  static_assert((O/(32*PAIR))*4 == 4*NTL, "work split mismatch");
  const int w = tid >> 6, lane = tid & 63, l31 = lane & 31, h = lane >> 5;

  const int u0 = w*NTL;
  const int rb  = u0 >> 2;        // row-block id
  const int nt0 = u0 & 3;         // first n-tile
  const int r0  = rb * 32*PAIR;

  const u16* aP[PAIR];
#pragma unroll
  for (int a = 0; a < PAIR; ++a)
    aP[a] = Wm + (size_t)(r0 + a*32 + l31)*K3 + h*8;

  int boff[NTL][3];
#pragma unroll
  for (int n = 0; n < NTL; ++n){
    int m = (nt0 + n)*32 + l31;   // position 0..127 (127 is pad, masked below)
#pragma unroll
    for (int j = 0; j < 3; ++j){
      int i = sidx[3*m + j];      // m==127 hits zero-padded sidx[381..383]
      boff[n][j] = i*SIN + h*8;
    }
  }

  float16v acc[NTL][PAIR];
#pragma unroll
  for (int n = 0; n < NTL; ++n)
#pragma unroll
    for (int a = 0; a < PAIR; ++a) acc[n][a] = {};

#pragma unroll
  for (int jk = 0; jk < NJK; ++jk){
    const int j    = jk / KS;
    const int coff = (jk - j*KS)*16;
    short8 A[PAIR];
#pragma unroll
    for (int a = 0; a < PAIR; ++a) A[a] = *(const short8*)(aP[a] + jk*16);
#pragma unroll
    for (int n = 0; n < NTL; ++n){
      short8 Bf = *(const short8*)(bIn + boff[n][j] + coff);
#pragma unroll
      for (int a = 0; a < PAIR; ++a)
        acc[n][a] = __builtin_amdgcn_mfma_f32_32x32x16_bf16(A[a], Bf, acc[n][a], 0, 0, 0);
    }
  }

  // post-loop: bias add (L2-hot loads, off the k-loop critical path) + stats
  float s = 0.f, s2 = 0.f;
#pragma unroll
  for (int n = 0; n < NTL; ++n){
    const int m = (nt0 + n)*32 + l31;
    const bool valid = (m <= 126);
#pragma unroll
    for (int a = 0; a < PAIR; ++a)
#pragma unroll
      for (int g = 0; g < 4; ++g){
        const int rowb = r0 + a*32 + 8*g + 4*h;
#pragma unroll
        for (int q = 0; q < 4; ++q){
          float raw = acc[n][a][4*g + q] + bias[rowb + q];
          acc[n][a][4*g + q] = raw;
          if (valid){ s += raw; s2 += raw*raw; }
        }
      }
  }

  // block-wide stats; this __syncthreads also FENCES all k-loop reads of bIn,
  // making it safe for the store phase below to overwrite bIn's region.
#pragma unroll
  for (int off = 32; off >= 1; off >>= 1){
    s  += __shfl_down(s,  off, 64);
    s2 += __shfl_down(s2, off, 64);
  }
  if (lane == 0){ sstat[w*2] = s; sstat[w*2+1] = s2; }
  __syncthreads();

  const float tot  = sstat[0] + sstat[2] + sstat[4] + sstat[6];
  const float tot2 = sstat[1] + sstat[3] + sstat[5] + sstat[7];
  constexpr float CNT = (float)(O * 128);
  const float mean = tot / CNT;
  float var = (tot2 - tot*mean) / (CNT - 1.f);   // unbiased, ddof=1
  var = fmaxf(var, 0.f);
  const float inv = 1.f / (sqrtf(var) + 1e-5f);
  *out_mean = mean; *out_inv = inv;

  // store phase (may alias the dead input region)
  if constexpr (!IS_L3){
#pragma unroll
    for (int n = 0; n < NTL; ++n){
      const int m = (nt0 + n)*32 + l31;
      const bool valid = (m <= 126);
#pragma unroll
      for (int a = 0; a < PAIR; ++a){
#pragma unroll
        for (int g = 0; g < 4; ++g){
          const int rowb = r0 + a*32 + 8*g + 4*h;
          ushort4v pk;
#pragma unroll
          for (int q = 0; q < 4; ++q){
            float f = (acc[n][a][4*g + q] - mean) * inv;
            if constexpr (LEAKY) f = lk(f);
            pk[q] = f2bf(f);
          }
          if (valid) *(ushort4v*)(bOut + (size_t)(m+1)*OST + rowb) = pk;
        }
      }
    }
    // node-0 row: normalized zero
    if (tid < O/8){
      float f0 = (0.f - mean) * inv;
      if constexpr (LEAKY) f0 = lk(f0);
      const u16 v0 = f2bf(f0);
      ushort8v z;
#pragma unroll
      for (int e = 0; e < 8; ++e) z[e] = v0;
      *(ushort8v*)(bOut + tid*8) = z;
    }
  } else {
    // raw fp32 (stride OST floats, odd -> conflict-free); maxpool applies
    // (max(raw)-mean)*inv via monotonicity. Node-0 raw == 0 handled by caller.
#pragma unroll
    for (int n = 0; n < NTL; ++n){
      const int m = (nt0 + n)*32 + l31;
      if (m <= 126){
#pragma unroll
        for (int a = 0; a < PAIR; ++a)
#pragma unroll
          for (int g = 0; g < 4; ++g){
            const int rowb = r0 + a*32 + 8*g + 4*h;
#pragma unroll
            for (int q = 0; q < 4; ++q)
              bOutF[(size_t)(m+1)*OST + rowb + q] = acc[n][a][4*g + q];
          }
      }
    }
  }
  __syncthreads();
}

// LDS: one 66 KB union buffer, reused by every stage:
//   trees in  [128 n][136] bf16   34816 B
//   L1 out    [128 n][264] bf16   67584 B  (over dead trees)
//   L2 out    [128 n][136] bf16   34816 B  (over dead L1)
//   L3 raw    [128 n][67]  fp32   34304 B  (over dead L2)
__global__ __launch_bounds__(256, 2) void bao_main(
    const float* __restrict__ trees, const int* __restrict__ gidx,
    const u16* __restrict__ wsW,
    const float* __restrict__ b1, const float* __restrict__ b2, const float* __restrict__ b3,
    const float* __restrict__ W4, const float* __restrict__ b4,
    const float* __restrict__ W5, const float* __restrict__ b5,
    float* __restrict__ dout)
{
  __shared__ __align__(16) u16 buf[33792];      // 67584 B union buffer
  __shared__ int   sidx[384];
  __shared__ float sstat[8];
  __shared__ float spoolP[256];
  __shared__ float spool[64];
  __shared__ float sh[32];

  const int tid = threadIdx.x;
  const int b = blockIdx.x;
  float* bufF = (float*)buf;

  // load + transpose + quantize trees[b] (fp32 [128 c][128 n] -> bf16 buf[n][c]).
  // Packed ds_write_b128; node-stride 17 super-banks => conflict-free.
  const float* tb = trees + (size_t)b * (128*128);
  {
    const int ngrp = tid & 31, cg = tid >> 5;
#pragma unroll
    for (int it = 0; it < 8; ++it){
      const int n  = ngrp + 32*(it & 3);
      const int c0 = (cg + 8*(it >> 2))*8;
      ushort8v pk;
#pragma unroll
      for (int cc = 0; cc < 8; ++cc) pk[cc] = f2bf(tb[(c0 + cc)*128 + n]);
      *(ushort8v*)(buf + n*136 + c0) = pk;
    }
  }
  // idx (381 entries, pad to 384 with 0)
  if (tid < 96){
#pragma unroll
    for (int k = 0; k < 4; ++k){
      int ii = tid*4 + k;
      sidx[ii] = (ii < 381) ? gidx[(size_t)b*381 + ii] : 0;
    }
  }
  __syncthreads();

  float mean, inv;
  //            CIN  O   SIN OST PAIR NTL LEAKY IS_L3
  do_layer<128,256,136,264, 4,  2, true ,false>(wsW,          b1, buf, buf, nullptr, sidx, sstat, tid, &mean, &inv);
  do_layer<256,128,264,136, 4,  1, true ,false>(wsW + 98304,  b2, buf, buf, nullptr, sidx, sstat, tid, &mean, &inv);
  do_layer<128, 64,136, 67, 2,  1, false,true >(wsW + 196608, b3, buf, nullptr, bufF, sidx, sstat, tid, &mean, &inv);

  // max-pool over nodes (raw fp32, stride 67); node-0 raw is exactly 0 so the
  // 0.f floor is exact. max(normalized) = (max(raw) - mean)*inv (monotone).
  {
    const int ch = tid & 63, seg = tid >> 6;
    float mx = 0.f;
    const int nd0 = seg*32 + (seg == 0 ? 1 : 0);
    for (int nd = nd0; nd < seg*32 + 32; ++nd) mx = fmaxf(mx, bufF[nd*67 + ch]);
    spoolP[seg*64 + ch] = mx;
  }
  __syncthreads();
  if (tid < 64){
    float mx = fmaxf(fmaxf(spoolP[tid], spoolP[64 + tid]),
                     fmaxf(spoolP[128 + tid], spoolP[192 + tid]));
    spool[tid] = (mx - mean) * inv;
  }
  __syncthreads();
  if (tid < 32){
    float a = b4[tid];
    for (int c = 0; c < 64; ++c) a += spool[c] * W4[tid*64 + c];
    sh[tid] = lk(a);
  }
  __syncthreads();
  if (tid == 0){
    float o = b5[0];
    for (int i = 0; i < 32; ++i) o += sh[i] * W5[i];
    dout[b] = o;
  }
}

extern "C" void kernel_launch(void* const* d_in, const int* in_sizes, int n_in,
                              void* d_out, int out_size, void* d_ws, size_t ws_size,
                              hipStream_t stream) {
  const float* trees = (const float*)d_in[0];
  const int*   gidx  = (const int*)d_in[1];
  const float* W1 = (const float*)d_in[2];
  const float* b1 = (const float*)d_in[3];
  const float* W2 = (const float*)d_in[4];
  const float* b2 = (const float*)d_in[5];
  const float* W3 = (const float*)d_in[6];
  const float* b3 = (const float*)d_in[7];
  const float* W4 = (const float*)d_in[8];
  const float* b4 = (const float*)d_in[9];
  const float* W5 = (const float*)d_in[10];
  const float* b5 = (const float*)d_in[11];
  u16* wsW = (u16*)d_ws;   // 221184 bf16 elems = 432 KB of permuted+quantized weights

  permute_w<<<864, 256, 0, stream>>>(W1, W2, W3, wsW);
  bao_main<<<2048, 256, 0, stream>>>(trees, gidx, wsW, b1, b2, b3, W4, b4, W5, b5,
                                     (float*)d_out);
}

// Round 7
// 442.089 us; speedup vs baseline: 1.1540x; 1.1540x over previous
//
#include <hip/hip_runtime.h>

typedef unsigned short u16;
typedef unsigned int   u32;
typedef __attribute__((ext_vector_type(8)))  short          short8;
typedef __attribute__((ext_vector_type(8)))  unsigned short ushort8v;
typedef __attribute__((ext_vector_type(4)))  unsigned short ushort4v;
typedef __attribute__((ext_vector_type(2)))  unsigned int   uint2v;
typedef __attribute__((ext_vector_type(16))) float          float16v;

__device__ __forceinline__ float bf2f(u16 u){
  union { unsigned int i; float f; } x; x.i = ((unsigned int)u) << 16; return x.f;
}
__device__ __forceinline__ u16 f2bf(float f){
  union { float f; unsigned int i; } x; x.f = f;
  unsigned int u = x.i;
  unsigned int r = (u + 0x7FFFu + ((u >> 16) & 1u)) >> 16;
  return (u16)r;
}
__device__ __forceinline__ float lk(float v){ return v > 0.f ? v : 0.01f*v; }

// ---------------- weight permute+quantize: Wmat[o][j*C+c] = bf16(W[o][c][j]) --
// ws layout (bf16 elems): Wmat1 @0 (256x384), Wmat2 @98304 (128x768), Wmat3 @196608 (64x384)
__global__ void permute_w(const float* __restrict__ W1, const float* __restrict__ W2,
                          const float* __restrict__ W3, u16* __restrict__ ws){
  int t = blockIdx.x*256 + threadIdx.x;
  const float* src; u16* dst; int C, local;
  if (t < 98304)       { src = W1; dst = ws;          C = 128; local = t; }
  else if (t < 196608) { src = W2; dst = ws + 98304;  C = 256; local = t - 98304; }
  else if (t < 221184) { src = W3; dst = ws + 196608; C = 128; local = t - 196608; }
  else return;
  int K3 = 3*C;
  int o = local / K3, r = local - o*K3;
  int j = r / C,      c = r - j*C;
  dst[local] = f2bf(src[o*K3 + c*3 + j]);
}

// generic k-loop: j in 0..2, t in [TS,TE); A offset (j*KSJ+t)*16, LDS c-offset
// t*16-CSUB. boff already includes node*136 + h*8.
template<int PAIR,int NTL,int KSJ,int TS,int TE,int CSUB>
__device__ __forceinline__ void kloop(const u16* const (&aP)[PAIR],
                                      const int (&boff)[NTL][3],
                                      const u16* bIn,
                                      float16v (&acc)[NTL][PAIR])
{
#pragma unroll
  for (int j = 0; j < 3; ++j)
#pragma unroll
    for (int t = TS; t < TE; ++t){
      const int aoff = (j*KSJ + t)*16;
      const int coff = t*16 - CSUB;
      short8 A[PAIR];
#pragma unroll
      for (int a = 0; a < PAIR; ++a) A[a] = *(const short8*)(aP[a] + aoff);
#pragma unroll
      for (int n = 0; n < NTL; ++n){
        short8 Bf = *(const short8*)(bIn + boff[n][j] + coff);
#pragma unroll
        for (int a = 0; a < PAIR; ++a)
          acc[n][a] = __builtin_amdgcn_mfma_f32_32x32x16_bf16(A[a], Bf, acc[n][a], 0, 0, 0);
      }
    }
}

// block-wide mean/inv from per-thread partials (ddof=1, count=CNT)
template<int CNT>
__device__ __forceinline__ void block_stats(float s, float s2, float* sstat,
                                            int w, int lane, float* mean, float* inv)
{
#pragma unroll
  for (int off = 32; off >= 1; off >>= 1){
    s  += __shfl_down(s,  off, 64);
    s2 += __shfl_down(s2, off, 64);
  }
  if (lane == 0){ sstat[w*2] = s; sstat[w*2+1] = s2; }
  __syncthreads();
  const float tot  = sstat[0] + sstat[2] + sstat[4] + sstat[6];
  const float tot2 = sstat[1] + sstat[3] + sstat[5] + sstat[7];
  const float m = tot / (float)CNT;
  float var = (tot2 - tot*m) / ((float)CNT - 1.f);
  var = fmaxf(var, 0.f);
  *mean = m; *inv = 1.f / (sqrtf(var) + 1e-5f);
}

// LDS: ONE 34.8 KB activation buffer, reused by every stage:
//   trees in      [128 n][136] bf16  (ch 0..127)
//   L1 out half   [128 n][136] bf16  (ch half, swapped mid-L2)
//   L2 out        [128 n][136] bf16
//   L3 raw        [128 n][67]  fp32
__global__ __launch_bounds__(256, 3) void bao_main(
    const float* __restrict__ trees, const int* __restrict__ gidx,
    const u16* __restrict__ wsW,
    const float* __restrict__ b1, const float* __restrict__ b2, const float* __restrict__ b3,
    const float* __restrict__ W4, const float* __restrict__ b4,
    const float* __restrict__ W5, const float* __restrict__ b5,
    float* __restrict__ dout)
{
  __shared__ __align__(16) u16 buf[17408];      // 34816 B
  __shared__ int   sidx[384];
  __shared__ float sstat[8];
  __shared__ float spoolP[256];
  __shared__ float spool[64];
  __shared__ float sh[32];

  const int tid = threadIdx.x;
  const int b = blockIdx.x;
  const int w = tid >> 6, lane = tid & 63, l31 = lane & 31, h = lane >> 5;
  float* bufF = (float*)buf;

  // ---- load + transpose + quantize trees[b] (fp32 [128 c][128 n] -> bf16 buf[n][c])
  const float* tb = trees + (size_t)b * (128*128);
  {
    const int ngrp = tid & 31, cg = tid >> 5;
#pragma unroll
    for (int it = 0; it < 8; ++it){
      const int n  = ngrp + 32*(it & 3);
      const int c0 = (cg + 8*(it >> 2))*8;
      ushort8v pk;
#pragma unroll
      for (int cc = 0; cc < 8; ++cc) pk[cc] = f2bf(tb[(c0 + cc)*128 + n]);
      *(ushort8v*)(buf + n*136 + c0) = pk;
    }
  }
  if (tid < 96){
#pragma unroll
    for (int k = 0; k < 4; ++k){
      int ii = tid*4 + k;
      sidx[ii] = (ii < 381) ? gidx[(size_t)b*381 + ii] : 0;
    }
  }
  __syncthreads();

  // =========== Layer 1: 256 out-ch; wave w -> rows w*64..+63, all 4 n-tiles ===
  const int r0_1 = w*64;
  const u16* aP1[2] = { wsW + (size_t)(r0_1      + l31)*384 + h*8,
                        wsW + (size_t)(r0_1 + 32 + l31)*384 + h*8 };
  int boff1[4][3];
#pragma unroll
  for (int n = 0; n < 4; ++n){
    const int m = n*32 + l31;
#pragma unroll
    for (int j = 0; j < 3; ++j) boff1[n][j] = sidx[3*m + j]*136 + h*8;
  }
  float16v acc1[4][2];
#pragma unroll
  for (int n = 0; n < 4; ++n){ acc1[n][0] = {}; acc1[n][1] = {}; }
  kloop<2,4,8,0,8,0>(aP1, boff1, buf, acc1);

  float s = 0.f, s2 = 0.f;
#pragma unroll
  for (int n = 0; n < 4; ++n){
    const int m = n*32 + l31;
    const bool valid = (m <= 126);
#pragma unroll
    for (int a = 0; a < 2; ++a)
#pragma unroll
      for (int g = 0; g < 4; ++g){
        const int rowb = r0_1 + a*32 + 8*g + 4*h;
#pragma unroll
        for (int q = 0; q < 4; ++q){
          float raw = acc1[n][a][4*g + q] + b1[rowb + q];
          acc1[n][a][4*g + q] = raw;
          if (valid){ s += raw; s2 += raw*raw; }
        }
      }
  }
  float mean, inv;
  block_stats<256*128>(s, s2, sstat, w, lane, &mean, &inv);  // barrier fences k-loop reads

  // pack normalized+leaky bf16 pairs: 64 u32 per lane (acc1 dies here)
  u32 packv[4][2][4][2];
#pragma unroll
  for (int n = 0; n < 4; ++n)
#pragma unroll
    for (int a = 0; a < 2; ++a)
#pragma unroll
      for (int g = 0; g < 4; ++g)
#pragma unroll
        for (int p = 0; p < 2; ++p){
          float lo = lk((acc1[n][a][4*g + 2*p    ] - mean) * inv);
          float hi = lk((acc1[n][a][4*g + 2*p + 1] - mean) * inv);
          packv[n][a][g][p] = (u32)f2bf(lo) | ((u32)f2bf(hi) << 16);
        }
  const u16 v01 = f2bf(lk((0.f - mean) * inv));   // L1 node-0 normalized zero

  // ---- store half ch0..127 (waves 0,1), node-0 row; then L2 phase 1 ----
  if (w < 2){
#pragma unroll
    for (int n = 0; n < 4; ++n){
      const int m = n*32 + l31;
      if (m <= 126){
#pragma unroll
        for (int a = 0; a < 2; ++a)
#pragma unroll
          for (int g = 0; g < 4; ++g){
            const int rowb = r0_1 + a*32 + 8*g + 4*h;  // 0..127
            uint2v dv = { packv[n][a][g][0], packv[n][a][g][1] };
            *(uint2v*)(buf + (m+1)*136 + rowb) = dv;
          }
      }
    }
  }
  if (tid < 16){
    ushort8v z;
#pragma unroll
    for (int e = 0; e < 8; ++e) z[e] = v01;
    *(ushort8v*)(buf + tid*8) = z;
  }
  __syncthreads();

  // =========== Layer 2: 128 out-ch; wave w -> rows (w>>1)*64, n-tiles (w*2)&3.. =
  const u16* wsW2 = wsW + 98304;
  const int r0_2  = (w >> 1)*64;
  const int nt0_2 = (w*2) & 3;
  const u16* aP2[2] = { wsW2 + (size_t)(r0_2      + l31)*768 + h*8,
                        wsW2 + (size_t)(r0_2 + 32 + l31)*768 + h*8 };
  int boff2[2][3];
#pragma unroll
  for (int n = 0; n < 2; ++n){
    const int m = (nt0_2 + n)*32 + l31;
#pragma unroll
    for (int j = 0; j < 3; ++j) boff2[n][j] = sidx[3*m + j]*136 + h*8;
  }
  float16v acc2[2][2];
  acc2[0][0] = {}; acc2[0][1] = {}; acc2[1][0] = {}; acc2[1][1] = {};
  kloop<2,2,16,0,8,0>(aP2, boff2, buf, acc2);     // K channels 0..127
  __syncthreads();                                 // everyone done reading half 1

  // store half ch128..255 (waves 2,3) over the same cols, node-0 row
  if (w >= 2){
#pragma unroll
    for (int n = 0; n < 4; ++n){
      const int m = n*32 + l31;
      if (m <= 126){
#pragma unroll
        for (int a = 0; a < 2; ++a)
#pragma unroll
          for (int g = 0; g < 4; ++g){
            const int rowb = r0_1 + a*32 + 8*g + 4*h;  // 128..255
            uint2v dv = { packv[n][a][g][0], packv[n][a][g][1] };
            *(uint2v*)(buf + (m+1)*136 + rowb - 128) = dv;
          }
      }
    }
  }
  if (tid < 16){
    ushort8v z;
#pragma unroll
    for (int e = 0; e < 8; ++e) z[e] = v01;
    *(ushort8v*)(buf + tid*8) = z;
  }
  __syncthreads();

  kloop<2,2,16,8,16,128>(aP2, boff2, buf, acc2);  // K channels 128..255

  s = 0.f; s2 = 0.f;
#pragma unroll
  for (int n = 0; n < 2; ++n){
    const int m = (nt0_2 + n)*32 + l31;
    const bool valid = (m <= 126);
#pragma unroll
    for (int a = 0; a < 2; ++a)
#pragma unroll
      for (int g = 0; g < 4; ++g){
        const int rowb = r0_2 + a*32 + 8*g + 4*h;
#pragma unroll
        for (int q = 0; q < 4; ++q){
          float raw = acc2[n][a][4*g + q] + b2[rowb + q];
          acc2[n][a][4*g + q] = raw;
          if (valid){ s += raw; s2 += raw*raw; }
        }
      }
  }
  block_stats<128*128>(s, s2, sstat, w, lane, &mean, &inv);  // fences phase-2 reads

  // store normalized L2 (128 ch) over the buffer
#pragma unroll
  for (int n = 0; n < 2; ++n){
    const int m = (nt0_2 + n)*32 + l31;
    if (m <= 126){
#pragma unroll
      for (int a = 0; a < 2; ++a)
#pragma unroll
        for (int g = 0; g < 4; ++g){
          const int rowb = r0_2 + a*32 + 8*g + 4*h;
          ushort4v pk;
#pragma unroll
          for (int q = 0; q < 4; ++q) pk[q] = f2bf(lk((acc2[n][a][4*g + q] - mean) * inv));
          *(ushort4v*)(buf + (m+1)*136 + rowb) = pk;
        }
    }
  }
  if (tid < 16){
    const u16 v02 = f2bf(lk((0.f - mean) * inv));
    ushort8v z;
#pragma unroll
    for (int e = 0; e < 8; ++e) z[e] = v02;
    *(ushort8v*)(buf + tid*8) = z;
  }
  __syncthreads();

  // =========== Layer 3: 64 out-ch; wave w -> rows 0..63, n-tile w ============
  const u16* wsW3 = wsW + 196608;
  const u16* aP3[2] = { wsW3 + (size_t)(l31)*384 + h*8,
                        wsW3 + (size_t)(32 + l31)*384 + h*8 };
  int boff3[1][3];
  {
    const int m = w*32 + l31;
#pragma unroll
    for (int j = 0; j < 3; ++j) boff3[0][j] = sidx[3*m + j]*136 + h*8;
  }
  float16v acc3[1][2];
  acc3[0][0] = {}; acc3[0][1] = {};
  kloop<2,1,8,0,8,0>(aP3, boff3, buf, acc3);

  s = 0.f; s2 = 0.f;
  {
    const int m = w*32 + l31;
    const bool valid = (m <= 126);
#pragma unroll
    for (int a = 0; a < 2; ++a)
#pragma unroll
      for (int g = 0; g < 4; ++g){
        const int rowb = a*32 + 8*g + 4*h;
#pragma unroll
        for (int q = 0; q < 4; ++q){
          float raw = acc3[0][a][4*g + q] + b3[rowb + q];
          acc3[0][a][4*g + q] = raw;
          if (valid){ s += raw; s2 += raw*raw; }
        }
      }
  }
  block_stats<64*128>(s, s2, sstat, w, lane, &mean, &inv);   // fences L3 k-loop reads

  // raw fp32 out, stride 67 (odd -> conflict-free), over the same buffer
  {
    const int m = w*32 + l31;
    if (m <= 126){
#pragma unroll
      for (int a = 0; a < 2; ++a)
#pragma unroll
        for (int g = 0; g < 4; ++g){
          const int rowb = a*32 + 8*g + 4*h;
#pragma unroll
          for (int q = 0; q < 4; ++q)
            bufF[(m+1)*67 + rowb + q] = acc3[0][a][4*g + q];
        }
    }
  }
  __syncthreads();

  // max-pool (monotone LN: max(normalized) = (max(raw)-mean)*inv; node-0 raw = 0)
  {
    const int ch = tid & 63, seg = tid >> 6;
    float mx = 0.f;
    const int nd0 = seg*32 + (seg == 0 ? 1 : 0);
    for (int nd = nd0; nd < seg*32 + 32; ++nd) mx = fmaxf(mx, bufF[nd*67 + ch]);
    spoolP[seg*64 + ch] = mx;
  }
  __syncthreads();
  if (tid < 64){
    float mx = fmaxf(fmaxf(spoolP[tid], spoolP[64 + tid]),
                     fmaxf(spoolP[128 + tid], spoolP[192 + tid]));
    spool[tid] = (mx - mean) * inv;
  }
  __syncthreads();
  if (tid < 32){
    float a = b4[tid];
    for (int c = 0; c < 64; ++c) a += spool[c] * W4[tid*64 + c];
    sh[tid] = lk(a);
  }
  __syncthreads();
  if (tid == 0){
    float o = b5[0];
    for (int i = 0; i < 32; ++i) o += sh[i] * W5[i];
    dout[b] = o;
  }
}

extern "C" void kernel_launch(void* const* d_in, const int* in_sizes, int n_in,
                              void* d_out, int out_size, void* d_ws, size_t ws_size,
                              hipStream_t stream) {
  const float* trees = (const float*)d_in[0];
  const int*   gidx  = (const int*)d_in[1];
  const float* W1 = (const float*)d_in[2];
  const float* b1 = (const float*)d_in[3];
  const float* W2 = (const float*)d_in[4];
  const float* b2 = (const float*)d_in[5];
  const float* W3 = (const float*)d_in[6];
  const float* b3 = (const float*)d_in[7];
  const float* W4 = (const float*)d_in[8];
  const float* b4 = (const float*)d_in[9];
  const float* W5 = (const float*)d_in[10];
  const float* b5 = (const float*)d_in[11];
  u16* wsW = (u16*)d_ws;   // 221184 bf16 elems = 432 KB of permuted+quantized weights

  permute_w<<<864, 256, 0, stream>>>(W1, W2, W3, wsW);
  bao_main<<<2048, 256, 0, stream>>>(trees, gidx, wsW, b1, b2, b3, W4, b4, W5, b5,
                                     (float*)d_out);
}

// Round 8
// 336.144 us; speedup vs baseline: 1.5177x; 1.3152x over previous
//
#include <hip/hip_runtime.h>

typedef unsigned short u16;
typedef __attribute__((ext_vector_type(8)))  short          short8;
typedef __attribute__((ext_vector_type(8)))  unsigned short ushort8v;
typedef __attribute__((ext_vector_type(4)))  unsigned short ushort4v;
typedef __attribute__((ext_vector_type(16))) float          float16v;

__device__ __forceinline__ float bf2f(u16 u){
  union { unsigned int i; float f; } x; x.i = ((unsigned int)u) << 16; return x.f;
}
__device__ __forceinline__ u16 f2bf(float f){
  union { float f; unsigned int i; } x; x.f = f;
  unsigned int u = x.i;
  unsigned int r = (u + 0x7FFFu + ((u >> 16) & 1u)) >> 16;
  return (u16)r;
}
__device__ __forceinline__ float lk(float v){ return v > 0.f ? v : 0.01f*v; }

// ------- weight permute+quantize into MFMA-fragment-TILED layout -------------
// Tile = (32 out-rows) x (one k-step of 16): 512 bf16 = 1 KB, stored as
// lane-major fragments: elem[(tile*64 + lane)*8 + e], where lane l holds
// A[row = rb*32 + (l&31)][k = jk*16 + (l>>5)*8 + e].  A-loads in the k-loop
// become ONE fully-coalesced 1 KB burst per instruction (vs 32 scattered
// 768B-strided lines in the naive row-major layout).
// ws layout (bf16): L1 @0 (8 rb x 24 jk tiles), L2 @98304 (4 x 48), L3 @196608 (2 x 24)
__global__ void permute_w(const float* __restrict__ W1, const float* __restrict__ W2,
                          const float* __restrict__ W3, u16* __restrict__ ws){
  int t = blockIdx.x*256 + threadIdx.x;
  const float* src; u16* dst; int C, local;
  if (t < 98304)       { src = W1; dst = ws;          C = 128; local = t; }
  else if (t < 196608) { src = W2; dst = ws + 98304;  C = 256; local = t - 98304; }
  else if (t < 221184) { src = W3; dst = ws + 196608; C = 128; local = t - 196608; }
  else return;
  const int NJK  = 3*C/16;
  const int tile = local >> 9, within = local & 511;
  const int lane = within >> 3, e = within & 7;
  const int rb = tile / NJK, jk = tile - rb*NJK;
  const int o  = rb*32 + (lane & 31);
  const int kg = jk*16 + (lane >> 5)*8 + e;
  const int j  = kg / C, c = kg - j*C;
  dst[local] = f2bf(src[o*3*C + c*3 + j]);
}

// ---------------- fused per-tree layer (4 waves, in-register output) ----------
// GEMM out[O x 127] = W[O x 3C] * G, where G[j*C+c][m] = bIn[idx[3m+j]][c]
// Wave w -> row-block (w*NTL)>>2 (64 rows, PAIR=2 tiles), n-tiles (w*NTL)&3..+NTL.
// Output stays in acc until after the stats __syncthreads (fences k-loop LDS
// reads), THEN is written to bOut/bOutF — which may ALIAS bIn.
template<int CIN, int O, int SIN, int OST, int NTL, bool LEAKY, bool IS_L3>
__device__ __forceinline__ void do_layer(const u16* __restrict__ Wt,
                                         const float* __restrict__ bias,
                                         const u16* bIn, u16* bOut, float* bOutF,
                                         const int* sidx, float* sstat,
                                         int tid, float* out_mean, float* out_inv)
{
  constexpr int KS  = CIN/16;     // k-steps per j segment
  constexpr int NJK = 3*KS;       // total k-steps
  static_assert((O/64)*4 == 4*NTL, "work split mismatch");
  const int w = tid >> 6, lane = tid & 63, l31 = lane & 31, h = lane >> 5;

  const int u0  = w*NTL;
  const int rb  = u0 >> 2;        // 64-row block id
  const int nt0 = u0 & 3;         // first n-tile
  const int r0  = rb * 64;

  // tiled A bases: tile index = (rb*2 + a)*NJK + jk, lane-major inside
  const u16* aP[2] = { Wt + ((size_t)(rb*2    )*NJK)*512 + lane*8,
                       Wt + ((size_t)(rb*2 + 1)*NJK)*512 + lane*8 };

  int boff[NTL][3];
#pragma unroll
  for (int n = 0; n < NTL; ++n){
    int m = (nt0 + n)*32 + l31;   // position 0..127 (127 is pad, masked below)
#pragma unroll
    for (int j = 0; j < 3; ++j){
      int i = sidx[3*m + j];      // m==127 hits zero-padded sidx[381..383]
      boff[n][j] = i*SIN + h*8;
    }
  }

  float16v acc[NTL][2];
#pragma unroll
  for (int n = 0; n < NTL; ++n){ acc[n][0] = {}; acc[n][1] = {}; }

#pragma unroll
  for (int jk = 0; jk < NJK; ++jk){
    const int j    = jk / KS;
    const int coff = (jk - j*KS)*16;
    short8 A0 = *(const short8*)(aP[0] + jk*512);
    short8 A1 = *(const short8*)(aP[1] + jk*512);
#pragma unroll
    for (int n = 0; n < NTL; ++n){
      short8 Bf = *(const short8*)(bIn + boff[n][j] + coff);
      acc[n][0] = __builtin_amdgcn_mfma_f32_32x32x16_bf16(A0, Bf, acc[n][0], 0, 0, 0);
      acc[n][1] = __builtin_amdgcn_mfma_f32_32x32x16_bf16(A1, Bf, acc[n][1], 0, 0, 0);
    }
  }

  // post-loop: bias add (L2-hot, off the k-loop critical path) + stats partials
  float s = 0.f, s2 = 0.f;
#pragma unroll
  for (int n = 0; n < NTL; ++n){
    const int m = (nt0 + n)*32 + l31;
    const bool valid = (m <= 126);
#pragma unroll
    for (int a = 0; a < 2; ++a)
#pragma unroll
      for (int g = 0; g < 4; ++g){
        const int rowb = r0 + a*32 + 8*g + 4*h;   // C/D row = (reg&3)+8*(reg>>2)+4h
#pragma unroll
        for (int q = 0; q < 4; ++q){
          float raw = acc[n][a][4*g + q] + bias[rowb + q];
          acc[n][a][4*g + q] = raw;
          if (valid){ s += raw; s2 += raw*raw; }
        }
      }
  }

  // block-wide stats; this __syncthreads also FENCES all k-loop reads of bIn,
  // making it safe for the store phase below to overwrite bIn's region.
#pragma unroll
  for (int off = 32; off >= 1; off >>= 1){
    s  += __shfl_down(s,  off, 64);
    s2 += __shfl_down(s2, off, 64);
  }
  if (lane == 0){ sstat[w*2] = s; sstat[w*2+1] = s2; }
  __syncthreads();

  const float tot  = sstat[0] + sstat[2] + sstat[4] + sstat[6];
  const float tot2 = sstat[1] + sstat[3] + sstat[5] + sstat[7];
  constexpr float CNT = (float)(O * 128);
  const float mean = tot / CNT;
  float var = (tot2 - tot*mean) / (CNT - 1.f);   // unbiased, ddof=1
  var = fmaxf(var, 0.f);
  const float inv = 1.f / (sqrtf(var) + 1e-5f);
  *out_mean = mean; *out_inv = inv;

  // store phase (may alias the dead input region)
  if constexpr (!IS_L3){
#pragma unroll
    for (int n = 0; n < NTL; ++n){
      const int m = (nt0 + n)*32 + l31;
      const bool valid = (m <= 126);
#pragma unroll
      for (int a = 0; a < 2; ++a){
#pragma unroll
        for (int g = 0; g < 4; ++g){
          const int rowb = r0 + a*32 + 8*g + 4*h;
          ushort4v pk;
#pragma unroll
          for (int q = 0; q < 4; ++q){
            float f = (acc[n][a][4*g + q] - mean) * inv;
            if constexpr (LEAKY) f = lk(f);
            pk[q] = f2bf(f);
          }
          if (valid) *(ushort4v*)(bOut + (size_t)(m+1)*OST + rowb) = pk;
        }
      }
    }
    // node-0 row: normalized zero
    if (tid < O/8){
      float f0 = (0.f - mean) * inv;
      if constexpr (LEAKY) f0 = lk(f0);
      const u16 v0 = f2bf(f0);
      ushort8v z;
#pragma unroll
      for (int e = 0; e < 8; ++e) z[e] = v0;
      *(ushort8v*)(bOut + tid*8) = z;
    }
  } else {
    // raw fp32 (stride OST floats, odd -> conflict-free); maxpool applies
    // (max(raw)-mean)*inv via monotonicity. Node-0 raw == 0 handled by caller.
#pragma unroll
    for (int n = 0; n < NTL; ++n){
      const int m = (nt0 + n)*32 + l31;
      if (m <= 126){
#pragma unroll
        for (int a = 0; a < 2; ++a)
#pragma unroll
          for (int g = 0; g < 4; ++g){
            const int rowb = r0 + a*32 + 8*g + 4*h;
#pragma unroll
            for (int q = 0; q < 4; ++q)
              bOutF[(size_t)(m+1)*OST + rowb + q] = acc[n][a][4*g + q];
          }
      }
    }
  }
  __syncthreads();
}

// LDS: one 66 KB union buffer, reused by every stage:
//   trees in  [128 n][136] bf16   34816 B
//   L1 out    [128 n][264] bf16   67584 B  (over dead trees)
//   L2 out    [128 n][136] bf16   34816 B  (over dead L1)
//   L3 raw    [128 n][67]  fp32   34304 B  (over dead L2)
__global__ __launch_bounds__(256, 2) void bao_main(
    const float* __restrict__ trees, const int* __restrict__ gidx,
    const u16* __restrict__ wsW,
    const float* __restrict__ b1, const float* __restrict__ b2, const float* __restrict__ b3,
    const float* __restrict__ W4, const float* __restrict__ b4,
    const float* __restrict__ W5, const float* __restrict__ b5,
    float* __restrict__ dout)
{
  __shared__ __align__(16) u16 buf[33792];      // 67584 B union buffer
  __shared__ int   sidx[384];
  __shared__ float sstat[8];
  __shared__ float spoolP[256];
  __shared__ float spool[64];
  __shared__ float sh[32];

  const int tid = threadIdx.x;
  const int b = blockIdx.x;
  float* bufF = (float*)buf;

  // load + transpose + quantize trees[b] (fp32 [128 c][128 n] -> bf16 buf[n][c]).
  // Packed ds_write_b128; node-stride 17 super-banks => conflict-free.
  const float* tb = trees + (size_t)b * (128*128);
  {
    const int ngrp = tid & 31, cg = tid >> 5;
#pragma unroll
    for (int it = 0; it < 8; ++it){
      const int n  = ngrp + 32*(it & 3);
      const int c0 = (cg + 8*(it >> 2))*8;
      ushort8v pk;
#pragma unroll
      for (int cc = 0; cc < 8; ++cc) pk[cc] = f2bf(tb[(c0 + cc)*128 + n]);
      *(ushort8v*)(buf + n*136 + c0) = pk;
    }
  }
  // idx (381 entries, pad to 384 with 0)
  if (tid < 96){
#pragma unroll
    for (int k = 0; k < 4; ++k){
      int ii = tid*4 + k;
      sidx[ii] = (ii < 381) ? gidx[(size_t)b*381 + ii] : 0;
    }
  }
  __syncthreads();

  float mean, inv;
  //            CIN  O   SIN OST NTL LEAKY IS_L3
  do_layer<128,256,136,264, 4, true ,false>(wsW,          b1, buf, buf, nullptr, sidx, sstat, tid, &mean, &inv);
  do_layer<256,128,264,136, 2, true ,false>(wsW + 98304,  b2, buf, buf, nullptr, sidx, sstat, tid, &mean, &inv);
  do_layer<128, 64,136, 67, 1, false,true >(wsW + 196608, b3, buf, nullptr, bufF, sidx, sstat, tid, &mean, &inv);

  // max-pool over nodes (raw fp32, stride 67); node-0 raw is exactly 0 so the
  // 0.f floor is exact. max(normalized) = (max(raw) - mean)*inv (monotone).
  {
    const int ch = tid & 63, seg = tid >> 6;
    float mx = 0.f;
    const int nd0 = seg*32 + (seg == 0 ? 1 : 0);
    for (int nd = nd0; nd < seg*32 + 32; ++nd) mx = fmaxf(mx, bufF[nd*67 + ch]);
    spoolP[seg*64 + ch] = mx;
  }
  __syncthreads();
  if (tid < 64){
    float mx = fmaxf(fmaxf(spoolP[tid], spoolP[64 + tid]),
                     fmaxf(spoolP[128 + tid], spoolP[192 + tid]));
    spool[tid] = (mx - mean) * inv;
  }
  __syncthreads();
  if (tid < 32){
    float a = b4[tid];
    for (int c = 0; c < 64; ++c) a += spool[c] * W4[tid*64 + c];
    sh[tid] = lk(a);
  }
  __syncthreads();
  if (tid == 0){
    float o = b5[0];
    for (int i = 0; i < 32; ++i) o += sh[i] * W5[i];
    dout[b] = o;
  }
}

extern "C" void kernel_launch(void* const* d_in, const int* in_sizes, int n_in,
                              void* d_out, int out_size, void* d_ws, size_t ws_size,
                              hipStream_t stream) {
  const float* trees = (const float*)d_in[0];
  const int*   gidx  = (const int*)d_in[1];
  const float* W1 = (const float*)d_in[2];
  const float* b1 = (const float*)d_in[3];
  const float* W2 = (const float*)d_in[4];
  const float* b2 = (const float*)d_in[5];
  const float* W3 = (const float*)d_in[6];
  const float* b3 = (const float*)d_in[7];
  const float* W4 = (const float*)d_in[8];
  const float* b4 = (const float*)d_in[9];
  const float* W5 = (const float*)d_in[10];
  const float* b5 = (const float*)d_in[11];
  u16* wsW = (u16*)d_ws;   // 221184 bf16 elems = 432 KB of tiled+quantized weights

  permute_w<<<864, 256, 0, stream>>>(W1, W2, W3, wsW);
  bao_main<<<2048, 256, 0, stream>>>(trees, gidx, wsW, b1, b2, b3, W4, b4, W5, b5,
                                     (float*)d_out);
}